// Round 7
// baseline (40.219 us; speedup 1.0000x reference)
//
#include <hip/hip_runtime.h>

#define IN_SZ 108
#define NPIX (IN_SZ * IN_SZ)

typedef float f32x2 __attribute__((ext_vector_type(2)));

__device__ __forceinline__ float maskv(float x, float off, float end) {
    // sigmoid(10*(x-off)) - sigmoid(10*(x-end))
    float a = 1.0f / (1.0f + __expf(-10.0f * (x - off)));
    float b = 1.0f / (1.0f + __expf(-10.0f * (x - end)));
    return a - b;
}

__global__ __launch_bounds__(256) void attn_crop_kernel(
    const float* __restrict__ images,
    const float* __restrict__ locs,
    float* __restrict__ out)
{
    __shared__ float4 s_row[IN_SZ];   // wr0, wr1, r0*108 (bits), r1*108 (bits)

    const int blk = blockIdx.x;       // img*3 + ch
    const int img = blk / 3;
    const int tid = threadIdx.x;
    const int w   = tid >> 6;         // wave id (0..3)
    const int l   = tid & 63;         // lane

    // ---- per-image box ----
    const float l0 = locs[3 * img + 0];
    const float l1 = locs[3 * img + 1];
    const float l2 = locs[3 * img + 2];
    const float tx = 54.0f + truncf(l0 * 27.0f + 0.5f);
    const float ty = 54.0f + truncf(l1 * 27.0f + 0.5f);
    const float tl = 21.0f + truncf(l2 * 7.0f + 0.5f);
    const float w_off = fmaxf(tx - tl, 0.0f);
    const float h_off = fmaxf(ty - tl, 0.0f);
    const float w_end = fminf(tx + tl, 108.0f);
    const float h_end = fminf(ty + tl, 108.0f);

    // ---- row table: built once (one expf pass, threads 0..107) ----
    if (tid < IN_SZ) {
        float fj  = (float)tid;
        float sr  = w_off + (fj * (w_end - w_off - 1.0f)) / 107.0f;  // reference order
        float flr = fminf(fmaxf(floorf(sr), 0.0f), 107.0f);
        int   r0  = (int)flr;
        int   r1  = min(r0 + 1, 107);
        float fr  = sr - flr;
        float4 p;
        p.x = (1.0f - fr) * maskv((float)r0, w_off, w_end);
        p.y = fr * maskv((float)r1, w_off, w_end);
        p.z = __int_as_float(r0 * IN_SZ);
        p.w = __int_as_float(r1 * IN_SZ);
        s_row[tid] = p;
    }

    // ---- per-lane column params (cols 2l, 2l+1), loop-invariant ----
    const float cspan = h_end - h_off - 1.0f;
    const int kA = min(2 * l, 107), kB = min(2 * l + 1, 107);
    float scA  = h_off + ((float)kA * cspan) / 107.0f;
    float flA  = fminf(fmaxf(floorf(scA), 0.0f), 107.0f);
    int   c0A  = (int)flA;
    float fcA  = scA - flA;
    float wc0A = (1.0f - fcA) * maskv((float)c0A, h_off, h_end);
    float wc1A = fcA * maskv((float)min(c0A + 1, 107), h_off, h_end);
    float scB  = h_off + ((float)kB * cspan) / 107.0f;
    float flB  = fminf(fmaxf(floorf(scB), 0.0f), 107.0f);
    int   c0B  = (int)flB;
    float fcB  = scB - flB;
    float wc0B = (1.0f - fcB) * maskv((float)c0B, h_off, h_end);
    float wc1B = fcB * maskv((float)min(c0B + 1, 107), h_off, h_end);

    // window cols {2li0, 2li0+1, 2li0+2, 2li0+3}; zero-weight taps proven exact
    const int li0 = c0A >> 1;
    const int par = c0A & 1;
    const int sy  = par + (c0B - c0A);
    // packed weights: WA/WB/WC multiply (q0,q0),(q1,q1),(q2,q2) -> (o.x, o.y)
    const f32x2 WA = { par ? 0.0f : wc0A,  (sy == 0) ? wc0B : 0.0f };
    const f32x2 WB = { par ? wc0A : wc1A,  (sy == 0) ? wc1B : ((sy == 1) ? wc0B : 0.0f) };
    const f32x2 WC = { par ? wc1A : 0.0f,  (sy == 1) ? wc1B : ((sy == 2) ? wc0B : 0.0f) };
    const float Wy3 = (sy == 2) ? wc1B : 0.0f;

    __syncthreads();

    const int colLoad = min(2 * l, 106);     // keep all lanes in-bounds
    const float* __restrict__ srcl = images + (size_t)blk * NPIX + colLoad;
    float*       __restrict__ dstl = out    + (size_t)blk * NPIX + 2 * l;
    const int jb = 27 * w;                   // contiguous rows [jb, jb+27) per wave

    // ---- prologue: rows 0,1 of this wave ----
    float4 pA = s_row[jb];
    float4 pB = s_row[jb + 1];
    f32x2 Aa = *(const f32x2*)(srcl + __float_as_int(pA.z));
    f32x2 Ba = *(const f32x2*)(srcl + __float_as_int(pA.w));
    f32x2 Ab = *(const f32x2*)(srcl + __float_as_int(pB.z));
    f32x2 Bb = *(const f32x2*)(srcl + __float_as_int(pB.w));

    for (int k = 0; k < 14; ++k) {
        // prefetch next iteration's two rows (clamped; row-26 dup near the tail)
        float4 pA2 = pA, pB2 = pB;
        f32x2 Aa2 = Aa, Ba2 = Ba, Ab2 = Ab, Bb2 = Bb;
        if (k < 13) {
            int a2 = 2 * k + 2, b2 = min(2 * k + 3, 26);
            pA2 = s_row[jb + a2];
            pB2 = s_row[jb + b2];
            Aa2 = *(const f32x2*)(srcl + __float_as_int(pA2.z));
            Ba2 = *(const f32x2*)(srcl + __float_as_int(pA2.w));
            Ab2 = *(const f32x2*)(srcl + __float_as_int(pB2.z));
            Bb2 = *(const f32x2*)(srcl + __float_as_int(pB2.w));
        }
        // ---- row a = jb + 2k (packed math: v_pk_fma_f32) ----
        {
            f32x2 M = Aa * pA.x + Ba * pA.y;
            float q0 = __shfl(M.x, li0);
            float q1 = __shfl(M.y, li0);
            float q2 = __shfl(M.x, li0 + 1);
            float q3 = __shfl(M.y, li0 + 1);
            f32x2 o = q0 * WA + q1 * WB + q2 * WC;
            o.y = fmaf(q3, Wy3, o.y);
            if (l < 54) *(f32x2*)(dstl + (jb + 2 * k) * IN_SZ) = o;
        }
        // ---- row b = jb + 2k + 1 (skipped at k=13) ----
        {
            f32x2 M = Ab * pB.x + Bb * pB.y;
            float q0 = __shfl(M.x, li0);
            float q1 = __shfl(M.y, li0);
            float q2 = __shfl(M.x, li0 + 1);
            float q3 = __shfl(M.y, li0 + 1);
            f32x2 o = q0 * WA + q1 * WB + q2 * WC;
            o.y = fmaf(q3, Wy3, o.y);
            if (l < 54 && 2 * k + 1 < 27) *(f32x2*)(dstl + (jb + 2 * k + 1) * IN_SZ) = o;
        }
        pA = pA2; pB = pB2;
        Aa = Aa2; Ba = Ba2; Ab = Ab2; Bb = Bb2;
    }
}

extern "C" void kernel_launch(void* const* d_in, const int* in_sizes, int n_in,
                              void* d_out, int out_size, void* d_ws, size_t ws_size,
                              hipStream_t stream) {
    const float* images = (const float*)d_in[0];
    const float* locs   = (const float*)d_in[1];
    float* out = (float*)d_out;
    const int nimg = in_sizes[1] / 3;   // locs is [nimg, 3]
    attn_crop_kernel<<<dim3(nimg * 3), dim3(256), 0, stream>>>(images, locs, out);
}